// Round 1
// 579.111 us; speedup vs baseline: 2.1471x; 2.1471x over previous
//
#include <hip/hip_runtime.h>
#include <cmath>

#define HW 307200        // 480*640
#define NB 8             // batches
#define NBASE 63         // input basis channels (ones channel prepended -> 64)
#define NCHUNK (HW/256)  // 1200 pixel chunks of 256
#define GRAM_BLKS 128    // gram blocks per batch
#define QCAP 320         // valid-pixel queue capacity (max 63 leftover + 256 new)

// ---- workspace layout (floats) ----
#define XTY_OFF 0                        // 8 * 64
#define YTY_OFF (NB*64)                  // 8
#define NC_OFF  (YTY_OFF + NB)           // 8
#define ZERO_FLOATS (NC_OFF + NB)        // atomic-accumulated region ends here (528)
#define XTX_OFF ZERO_FLOATS              // 8 * 64*64 (written whole by reduce_kernel)
#define MP_OFF  (XTX_OFF + NB*64*64)     // 8 * 64*64 (upper-tri M, diag halved, /beta)
#define WV_OFF  (MP_OFF + NB*64*64)      // 8 * 64

// ---- output layout (floats) ----
#define OUT_W   (NB*HW)                  // weights after logits
#define OUT_VAR (OUT_W + NB*64)          // var after weights
// NOTE: gram partials (8*128*4096 = 4.19M floats) are staged in out[0..),
// consumed by reduce_kernel BEFORE solve/predvar overwrite out. Stream-ordered.

__device__ __forceinline__ bool finitef(float x) {
    // fast-math-proof isfinite: exponent bits not all ones
    return (__float_as_uint(x) & 0x7f800000u) != 0x7f800000u;
}

// ============================================================
// Kernel 1: sparse masked Gram. Only ~5% of pixels are valid
// (targets finite), so: scan targets coalesced, compact valid
// {pixel,y} into an LDS queue, and per 64 queued pixels gather
// the 63 basis channels (lane = channel -> conflict-free LDS
// writes) and run the 8x8 register-tile outer product.
// Per-wave accs are LDS-reduced; each block stores ONE coalesced
// 16KB partial (no global atomics for XtX).
// ============================================================
__global__ __launch_bounds__(256) void gram_kernel(
    const float* __restrict__ bases, const float* __restrict__ targets,
    float* __restrict__ ws, float* __restrict__ part)
{
    __shared__ float tile[64*68];   // [pixel][channel], stride 68; tail reused for Xty reduce
    __shared__ float sy[64];
    __shared__ float qy[QCAP];
    __shared__ int   qidx[QCAP];
    __shared__ int   qn;

    const int t  = threadIdx.x;
    const int b  = blockIdx.y;
    const int wv = t >> 6;          // wave id 0..3
    const int l  = t & 63;          // lane
    const int ti = l >> 3, tj = l & 7;

    float acc[8][8];
#pragma unroll
    for (int i = 0; i < 8; i++)
#pragma unroll
        for (int j = 0; j < 8; j++) acc[i][j] = 0.f;
    float acc_xty = 0.f, acc_yty = 0.f, acc_n = 0.f;

    const float* __restrict__ basesb = bases + (long)b * NBASE * HW;
    const float* __restrict__ targb  = targets + (long)b * HW;
    const long choff = (long)(l - 1) * HW;   // this lane's channel plane (lane 0 = ones)

    if (t == 0) qn = 0;
    __syncthreads();

    auto compute_tile = [&]() {
#pragma unroll 2
        for (int pp = 0; pp < 16; ++pp) {
            const int p2 = wv * 16 + pp;
            const float4 r0 = *(const float4*)&tile[p2*68 + 8*ti];
            const float4 r1 = *(const float4*)&tile[p2*68 + 8*ti + 4];
            const float4 c0 = *(const float4*)&tile[p2*68 + 8*tj];
            const float4 c1 = *(const float4*)&tile[p2*68 + 8*tj + 4];
            const float rr[8] = {r0.x,r0.y,r0.z,r0.w,r1.x,r1.y,r1.z,r1.w};
            const float cc[8] = {c0.x,c0.y,c0.z,c0.w,c1.x,c1.y,c1.z,c1.w};
#pragma unroll
            for (int i = 0; i < 8; i++)
#pragma unroll
                for (int j = 0; j < 8; j++)
                    acc[i][j] = fmaf(rr[i], cc[j], acc[i][j]);
            // Xty: lane l owns channel l
            acc_xty = fmaf(sy[p2], tile[p2*68 + l], acc_xty);
        }
    };

    int qtot = 0;
    for (int j = blockIdx.x; j < NCHUNK; j += GRAM_BLKS) {
        // ---- append phase: coalesced target read, ballot-compact valid pixels ----
        const int p = j * 256 + t;
        const float y = targb[p];
        const bool fin = finitef(y);
        const unsigned long long m = __ballot(fin);
        int wbase = 0;
        if (l == 0) wbase = atomicAdd(&qn, __popcll(m));
        wbase = __shfl(wbase, 0, 64);
        if (fin) {
            const int r = __popcll(m & ((1ull << l) - 1ull));
            qidx[wbase + r] = p;
            qy[wbase + r]   = y;
            acc_yty = fmaf(y, y, acc_yty);
            acc_n += 1.f;
        }
        __syncthreads();
        qtot = qn;
        // ---- drain phase: gather + Gram per full 64-pixel tile (stack order) ----
        while (qtot >= 64) {
            const int base = qtot - 64;
            if (t < 64) sy[t] = qy[base + t];
#pragma unroll
            for (int pp = wv; pp < 64; pp += 4) {   // 16 independent gathers/thread
                const int gp = qidx[base + pp];     // LDS broadcast
                float v;
                if (l == 0) v = 1.f;                // ones channel (valid pixel)
                else        v = basesb[choff + gp];
                tile[pp*68 + l] = v;                // lane-contiguous: conflict-free
            }
            __syncthreads();
            compute_tile();
            qtot -= 64;
            __syncthreads();
        }
        if (t == 0) qn = qtot;
        __syncthreads();
    }

    // ---- flush remainder (<64 pixels) with zero padding ----
    if (qtot > 0) {
        if (t < 64) sy[t] = (t < qtot) ? qy[t] : 0.f;
#pragma unroll
        for (int pp = wv; pp < 64; pp += 4) {
            float v = 0.f;
            if (pp < qtot) {
                const int gp = qidx[pp];
                if (l == 0) v = 1.f;
                else        v = basesb[choff + gp];
            }
            tile[pp*68 + l] = v;
        }
        __syncthreads();
        compute_tile();
    }
    __syncthreads();

    // ---- cross-wave reduce of acc tiles into tile[0..4096) ----
    for (int w = 0; w < 4; ++w) {
        if (wv == w) {
#pragma unroll
            for (int i = 0; i < 8; i++)
#pragma unroll
                for (int j2 = 0; j2 < 8; j2++) {
                    const int e = (8*ti + i) * 64 + 8*tj + j2;
                    tile[e] = (w == 0) ? acc[i][j2] : tile[e] + acc[i][j2];
                }
        }
        __syncthreads();
    }
    // one coalesced 16KB partial per block, no atomics
    float* __restrict__ pb = part + (long)(b * GRAM_BLKS + blockIdx.x) * 4096;
#pragma unroll
    for (int k = 0; k < 4; ++k)
        *(float4*)&pb[t*16 + 4*k] = *(const float4*)&tile[t*16 + 4*k];

    // Xty: cross-wave reduce into tile[4096..4160), then 64 atomics/block
    for (int w = 0; w < 4; ++w) {
        if (wv == w) tile[4096 + l] = (w == 0) ? acc_xty : tile[4096 + l] + acc_xty;
        __syncthreads();
    }
    if (t < 64) atomicAdd(&ws[XTY_OFF + b*64 + t], tile[4096 + t]);

    // yty, N: wave shuffle reduce + one atomic per wave
#pragma unroll
    for (int off = 32; off; off >>= 1) {
        acc_yty += __shfl_down(acc_yty, off, 64);
        acc_n   += __shfl_down(acc_n,   off, 64);
    }
    if (l == 0) {
        atomicAdd(&ws[YTY_OFF + b], acc_yty);
        atomicAdd(&ws[NC_OFF  + b], acc_n);
    }
}

// ============================================================
// Kernel 1b: sum the 128 per-block XtX partials -> ws (coalesced)
// ============================================================
__global__ __launch_bounds__(256) void reduce_kernel(
    const float* __restrict__ part, float* __restrict__ ws)
{
    const int b = blockIdx.y;
    const int e = blockIdx.x * 256 + threadIdx.x;   // grid.x = 16 -> e in [0,4096)
    const float* __restrict__ pb = part + (long)b * GRAM_BLKS * 4096 + e;
    float s = 0.f;
#pragma unroll 8
    for (int k = 0; k < GRAM_BLKS; ++k)
        s += pb[(long)k * 4096];
    ws[XTX_OFF + b*4096 + e] = s;
}

// ============================================================
// Kernel 2: per batch (8 blocks x 64 threads = 1 wave):
// Cholesky(XtX), explicit inverse, w = XtX^-1 Xty,
// E_d = yty - 2 w.Xty + w.XtX.w, EM beta loop (done-latched),
// emit weights to d_out, and Mp (upper-tri, diag*0.5, * 1/beta) + w to ws.
// ============================================================
__global__ __launch_bounds__(64) void solve_kernel(
    float* __restrict__ ws, float* __restrict__ out)
{
    __shared__ float A[64*65];
    __shared__ float W[64*65];
    __shared__ float d0[64], xty[64], wv_s[64];

    const int b = blockIdx.x;
    const int t = threadIdx.x;
    const float* XtX = ws + XTX_OFF + b * 4096;

    for (int j = 0; j < 64; j++) A[t*65 + j] = XtX[t*64 + j];
    xty[t] = ws[XTY_OFF + b*64 + t];
    d0[t]  = A[t*65 + t];
    const float yty = ws[YTY_OFF + b];
    const float Nc  = ws[NC_OFF  + b];
    __syncthreads();

    // Cholesky (lower), upper triangle keeps original XtX
    for (int k = 0; k < 64; k++) {
        float akk = A[k*65 + k];
        __syncthreads();
        float dk = sqrtf(akk);
        if (t == k)      A[k*65 + k] = dk;
        else if (t > k)  A[t*65 + k] = A[t*65 + k] / dk;
        __syncthreads();
        if (t > k) {
            float ltk = A[t*65 + k];
            for (int j = k + 1; j <= t; j++)
                A[t*65 + j] -= ltk * A[j*65 + k];
        }
        __syncthreads();
    }

    // inverse: thread t solves column t of (L L^T)^-1
    for (int i = 0; i < 64; i++) {
        float s = (i == t) ? 1.f : 0.f;
        for (int j = 0; j < i; j++) s = fmaf(-A[i*65 + j], W[j*65 + t], s);
        W[i*65 + t] = s / A[i*65 + i];
    }
    for (int i = 63; i >= 0; i--) {
        float s = W[i*65 + t];
        for (int j = i + 1; j < 64; j++) s = fmaf(-A[j*65 + i], W[j*65 + t], s);
        W[i*65 + t] = s / A[i*65 + i];
    }
    __syncthreads();

    // w = Minv @ Xty
    float wt = 0.f;
    for (int j = 0; j < 64; j++) wt = fmaf(W[t*65 + j], xty[j], wt);
    wv_s[t] = wt;
    __syncthreads();

    // E_d = yty - 2 w.Xty + w.(XtX w)   (XtX from upper triangle + saved diag)
    float qt = 0.f;
    for (int j = 0; j < 64; j++) {
        float x = (j > t) ? A[t*65 + j] : ((j == t) ? d0[t] : A[j*65 + t]);
        qt = fmaf(x, wv_s[j], qt);
    }
    float r1 = wt * xty[t];
    float r2 = wt * qt;
#pragma unroll
    for (int off = 32; off; off >>= 1) {
        r1 += __shfl_down(r1, off, 64);
        r2 += __shfl_down(r2, off, 64);
    }
    r1 = __shfl(r1, 0, 64);
    r2 = __shfl(r2, 0, 64);
    const float E_d = yty - 2.f * r1 + r2;

    // EM beta loop, faithful to reference latch order
    float beta0 = sqrtf(Nc);
    float beta  = beta0;
    bool  done  = false;
#pragma unroll
    for (int it = 0; it < 5; ++it) {
        float Tr_d = 64.f / beta;
        float beta_new = Nc / (E_d + Tr_d);
        bool conv = fabsf(beta_new / beta0 - 1.f) < 0.02f;
        if (!done) { beta = beta_new; beta0 = beta_new; }
        done = done || conv;
    }
    const float ib = 1.f / beta;

    out[OUT_W + b*64 + t] = wt;
    ws[WV_OFF + b*64 + t] = wt;
    float* Mp = ws + MP_OFF + b * 4096;
    for (int j = 0; j < 64; j++) {
        float v = (j < t) ? 0.f : ((j == t) ? 0.5f : 1.f) * W[t*65 + j] * ib;
        Mp[t*64 + j] = v;
    }
}

// ============================================================
// Kernel 3: per pixel: pred = w.b (ones channel incl),
// var = 2 * sum_i b_i * sum_{j>=i} Mp[i][j] b_j
// M/w accessed via wave-uniform indices -> scalar loads (SGPR operands),
// b held in 64 VGPRs via fully unrolled triangular loops.
// ============================================================
__global__ __launch_bounds__(256) void predvar_kernel(
    const float* __restrict__ bases, const float* __restrict__ ws,
    float* __restrict__ out)
{
    const int b   = blockIdx.y;
    const int pix = blockIdx.x * 256 + threadIdx.x;
    const float* __restrict__ Mp = ws + MP_OFF + b * 4096;
    const float* __restrict__ wb = ws + WV_OFF + b * 64;
    const float* basesb = bases + (long)b * NBASE * HW + pix;

    float bv[64];
    bv[0] = 1.f;
#pragma unroll
    for (int c = 1; c < 64; c++) bv[c] = basesb[(long)(c - 1) * HW];

    float pred = wb[0];
#pragma unroll
    for (int c = 1; c < 64; c++) pred = fmaf(wb[c], bv[c], pred);

    float var2 = 0.f;
#pragma unroll
    for (int i = 0; i < 64; i++) {
        float si = 0.f;
#pragma unroll
        for (int j = i; j < 64; j++) si = fmaf(Mp[i*64 + j], bv[j], si);
        var2 = fmaf(si, bv[i], var2);
    }

    out[(long)b * HW + pix] = pred;
    out[OUT_VAR + (long)b * HW + pix] = 2.f * var2;
}

extern "C" void kernel_launch(void* const* d_in, const int* in_sizes, int n_in,
                              void* d_out, int out_size, void* d_ws, size_t ws_size,
                              hipStream_t stream)
{
    const float* bases   = (const float*)d_in[0];
    const float* targets = (const float*)d_in[1];
    float* out = (float*)d_out;
    float* ws  = (float*)d_ws;

    // zero only the atomic-accumulated region (Xty/yty/N); XtX is written whole
    hipMemsetAsync(d_ws, 0, ZERO_FLOATS * sizeof(float), stream);

    // XtX partials staged in out[] (dead until reduce consumes them)
    gram_kernel<<<dim3(GRAM_BLKS, NB), 256, 0, stream>>>(bases, targets, ws, out);
    reduce_kernel<<<dim3(16, NB), 256, 0, stream>>>(out, ws);
    solve_kernel<<<NB, 64, 0, stream>>>(ws, out);
    predvar_kernel<<<dim3(HW / 256, NB), 256, 0, stream>>>(bases, ws, out);
}

// Round 2
// 578.319 us; speedup vs baseline: 2.1500x; 1.0014x over previous
//
#include <hip/hip_runtime.h>
#include <cmath>

#define HW 307200        // 480*640
#define NB 8             // batches
#define NBASE 63         // input basis channels (ones channel prepended -> 64)
#define NCHUNK (HW/256)  // 1200 pixel chunks of 256
#define GRAM_BLKS 128    // gram blocks per batch
#define QCAP 320         // valid-pixel queue capacity (max 63 leftover + 256 new)

// ---- workspace layout (floats) ----
#define XTY_OFF 0                        // 8 * 64
#define YTY_OFF (NB*64)                  // 8
#define NC_OFF  (YTY_OFF + NB)           // 8
#define ZERO_FLOATS (NC_OFF + NB)        // atomic-accumulated region ends here (528)
#define XTX_OFF ZERO_FLOATS              // 8 * 64*64 (written whole by reduce_kernel)
#define MP_OFF  (XTX_OFF + NB*64*64)     // 8 * 64*64 (upper-tri M, diag halved, /beta)
#define WV_OFF  (MP_OFF + NB*64*64)      // 8 * 64

// ---- output layout (floats) ----
#define OUT_W   (NB*HW)                  // weights after logits
#define OUT_VAR (OUT_W + NB*64)          // var after weights
// NOTE: gram partials (8*128*4096 = 4.19M floats = 16.8MB) are staged in out[],
// consumed by reduce_kernel BEFORE solve/predvar overwrite out. Stream-ordered.

__device__ __forceinline__ bool finitef(float x) {
    // fast-math-proof isfinite: exponent bits not all ones
    return (__float_as_uint(x) & 0x7f800000u) != 0x7f800000u;
}

// ============================================================
// Kernel 1: sparse masked Gram. Only ~5% of pixels are valid
// (targets finite): scan targets coalesced, compact valid
// {pixel,y} into an LDS queue, and per 64 queued pixels gather
// the 63 basis channels (lane = channel -> conflict-free LDS
// writes) and run the 8x8 register-tile outer product.
// Per-wave accs are LDS-reduced; each block stores ONE coalesced
// 16KB partial (no global atomics for XtX).
// ============================================================
__global__ __launch_bounds__(256) void gram_kernel(
    const float* __restrict__ bases, const float* __restrict__ targets,
    float* __restrict__ ws, float* __restrict__ part)
{
    __shared__ float tile[64*68];   // [pixel][channel], stride 68; tail reused for Xty reduce
    __shared__ float sy[64];
    __shared__ float qy[QCAP];
    __shared__ int   qidx[QCAP];
    __shared__ int   qn;

    const int t  = threadIdx.x;
    const int b  = blockIdx.y;
    const int wv = t >> 6;          // wave id 0..3
    const int l  = t & 63;          // lane
    const int ti = l >> 3, tj = l & 7;

    float acc[8][8];
#pragma unroll
    for (int i = 0; i < 8; i++)
#pragma unroll
        for (int j = 0; j < 8; j++) acc[i][j] = 0.f;
    float acc_xty = 0.f, acc_yty = 0.f, acc_n = 0.f;

    const float* __restrict__ basesb = bases + (long)b * NBASE * HW;
    const float* __restrict__ targb  = targets + (long)b * HW;
    const long choff = (long)(l - 1) * HW;   // this lane's channel plane (lane 0 = ones)

    if (t == 0) qn = 0;
    __syncthreads();

    auto compute_tile = [&]() {
#pragma unroll 2
        for (int pp = 0; pp < 16; ++pp) {
            const int p2 = wv * 16 + pp;
            const float4 r0 = *(const float4*)&tile[p2*68 + 8*ti];
            const float4 r1 = *(const float4*)&tile[p2*68 + 8*ti + 4];
            const float4 c0 = *(const float4*)&tile[p2*68 + 8*tj];
            const float4 c1 = *(const float4*)&tile[p2*68 + 8*tj + 4];
            const float rr[8] = {r0.x,r0.y,r0.z,r0.w,r1.x,r1.y,r1.z,r1.w};
            const float cc[8] = {c0.x,c0.y,c0.z,c0.w,c1.x,c1.y,c1.z,c1.w};
#pragma unroll
            for (int i = 0; i < 8; i++)
#pragma unroll
                for (int j = 0; j < 8; j++)
                    acc[i][j] = fmaf(rr[i], cc[j], acc[i][j]);
            // Xty: lane l owns channel l
            acc_xty = fmaf(sy[p2], tile[p2*68 + l], acc_xty);
        }
    };

    int qtot = 0;
    for (int j = blockIdx.x; j < NCHUNK; j += GRAM_BLKS) {
        // ---- append phase: coalesced target read, ballot-compact valid pixels ----
        const int p = j * 256 + t;
        const float y = targb[p];
        const bool fin = finitef(y);
        const unsigned long long m = __ballot(fin);
        int wbase = 0;
        if (l == 0) wbase = atomicAdd(&qn, __popcll(m));
        wbase = __shfl(wbase, 0, 64);
        if (fin) {
            const int r = __popcll(m & ((1ull << l) - 1ull));
            qidx[wbase + r] = p;
            qy[wbase + r]   = y;
            acc_yty = fmaf(y, y, acc_yty);
            acc_n += 1.f;
        }
        __syncthreads();
        qtot = qn;
        // ---- drain phase: gather + Gram per full 64-pixel tile (stack order) ----
        while (qtot >= 64) {
            const int base = qtot - 64;
            if (t < 64) sy[t] = qy[base + t];
#pragma unroll
            for (int pp = wv; pp < 64; pp += 4) {   // 16 independent gathers/thread
                const int gp = qidx[base + pp];     // LDS broadcast
                float v;
                if (l == 0) v = 1.f;                // ones channel (valid pixel)
                else        v = basesb[choff + gp];
                tile[pp*68 + l] = v;                // lane-contiguous: conflict-free
            }
            __syncthreads();
            compute_tile();
            qtot -= 64;
            __syncthreads();
        }
        if (t == 0) qn = qtot;
        __syncthreads();
    }

    // ---- flush remainder (<64 pixels) with zero padding ----
    if (qtot > 0) {
        if (t < 64) sy[t] = (t < qtot) ? qy[t] : 0.f;
#pragma unroll
        for (int pp = wv; pp < 64; pp += 4) {
            float v = 0.f;
            if (pp < qtot) {
                const int gp = qidx[pp];
                if (l == 0) v = 1.f;
                else        v = basesb[choff + gp];
            }
            tile[pp*68 + l] = v;
        }
        __syncthreads();
        compute_tile();
    }
    __syncthreads();

    // ---- cross-wave reduce of acc tiles into tile[0..4096) ----
    for (int w = 0; w < 4; ++w) {
        if (wv == w) {
#pragma unroll
            for (int i = 0; i < 8; i++)
#pragma unroll
                for (int j2 = 0; j2 < 8; j2++) {
                    const int e = (8*ti + i) * 64 + 8*tj + j2;
                    tile[e] = (w == 0) ? acc[i][j2] : tile[e] + acc[i][j2];
                }
        }
        __syncthreads();
    }
    // one coalesced 16KB partial per block, no atomics
    float* __restrict__ pb = part + (long)(b * GRAM_BLKS + blockIdx.x) * 4096;
#pragma unroll
    for (int k = 0; k < 4; ++k)
        *(float4*)&pb[t*16 + 4*k] = *(const float4*)&tile[t*16 + 4*k];

    // Xty: cross-wave reduce into tile[4096..4160), then 64 atomics/block
    for (int w = 0; w < 4; ++w) {
        if (wv == w) tile[4096 + l] = (w == 0) ? acc_xty : tile[4096 + l] + acc_xty;
        __syncthreads();
    }
    if (t < 64) atomicAdd(&ws[XTY_OFF + b*64 + t], tile[4096 + t]);

    // yty, N: wave shuffle reduce + one atomic per wave
#pragma unroll
    for (int off = 32; off; off >>= 1) {
        acc_yty += __shfl_down(acc_yty, off, 64);
        acc_n   += __shfl_down(acc_n,   off, 64);
    }
    if (l == 0) {
        atomicAdd(&ws[YTY_OFF + b], acc_yty);
        atomicAdd(&ws[NC_OFF  + b], acc_n);
    }
}

// ============================================================
// Kernel 1b: sum the 128 per-block XtX partials -> ws (coalesced)
// ============================================================
__global__ __launch_bounds__(256) void reduce_kernel(
    const float* __restrict__ part, float* __restrict__ ws)
{
    const int b = blockIdx.y;
    const int e = blockIdx.x * 256 + threadIdx.x;   // grid.x = 16 -> e in [0,4096)
    const float* __restrict__ pb = part + (long)b * GRAM_BLKS * 4096 + e;
    float s = 0.f;
#pragma unroll 8
    for (int k = 0; k < GRAM_BLKS; ++k)
        s += pb[(long)k * 4096];
    ws[XTX_OFF + b*4096 + e] = s;
}

// ============================================================
// Kernel 2: per batch, 256 threads (4 waves):
// Cholesky update 4-way parallel over columns; inverse/w/E_d on
// wave 0 (column-serial chains); staging + Mp emit on all 256.
// ============================================================
__global__ __launch_bounds__(256) void solve_kernel(
    float* __restrict__ ws, float* __restrict__ out)
{
    __shared__ float A[64*65];
    __shared__ float W[64*65];
    __shared__ float d0[64], xty_s[64], wv_s[64];
    __shared__ float ib_s;

    const int b = blockIdx.x;
    const int t = threadIdx.x;
    const int r = t & 63;           // row / lane
    const int q = t >> 6;           // wave id
    const float* XtX = ws + XTX_OFF + b * 4096;

    for (int e = t; e < 4096; e += 256)
        A[(e >> 6) * 65 + (e & 63)] = XtX[e];
    if (t < 64) xty_s[t] = ws[XTY_OFF + b*64 + t];
    const float yty = ws[YTY_OFF + b];
    const float Nc  = ws[NC_OFF  + b];
    __syncthreads();
    if (t < 64) d0[t] = A[t*65 + t];
    __syncthreads();

    // Cholesky (lower), upper triangle keeps original XtX.
    // Rank-1 update split across the 4 waves by j-stride.
    for (int k = 0; k < 64; k++) {
        const float akk = A[k*65 + k];
        __syncthreads();
        const float dk = sqrtf(akk);
        if (q == 0) {
            if (r == k)     A[k*65 + k] = dk;
            else if (r > k) A[r*65 + k] /= dk;
        }
        __syncthreads();
        if (r > k) {
            const float lrk = A[r*65 + k];
            for (int j = k + 1 + q; j <= r; j += 4)
                A[r*65 + j] -= lrk * A[j*65 + k];
        }
        __syncthreads();
    }

    // inverse + w + E_d: wave 0, thread r = column r
    if (q == 0) {
        for (int i = 0; i < 64; i++) {
            float s = (i == r) ? 1.f : 0.f;
            for (int j = 0; j < i; j++) s = fmaf(-A[i*65 + j], W[j*65 + r], s);
            W[i*65 + r] = s / A[i*65 + i];
        }
        for (int i = 63; i >= 0; i--) {
            float s = W[i*65 + r];
            for (int j = i + 1; j < 64; j++) s = fmaf(-A[j*65 + i], W[j*65 + r], s);
            W[i*65 + r] = s / A[i*65 + i];
        }
        // w = Minv @ Xty
        float wt = 0.f;
        for (int j = 0; j < 64; j++) wt = fmaf(W[r*65 + j], xty_s[j], wt);
        wv_s[r] = wt;

        // E_d = yty - 2 w.Xty + w.(XtX w)  (XtX from upper triangle + saved diag)
        float qt = 0.f;
        for (int j = 0; j < 64; j++) {
            float x = (j > r) ? A[r*65 + j] : ((j == r) ? d0[r] : A[j*65 + r]);
            qt = fmaf(x, wv_s[j], qt);
        }
        float r1 = wt * xty_s[r];
        float r2 = wt * qt;
#pragma unroll
        for (int off = 32; off; off >>= 1) {
            r1 += __shfl_down(r1, off, 64);
            r2 += __shfl_down(r2, off, 64);
        }
        if (r == 0) {
            const float E_d = yty - 2.f * r1 + r2;
            // EM beta loop, faithful to reference latch order
            float beta0 = sqrtf(Nc);
            float beta  = beta0;
            bool  done  = false;
#pragma unroll
            for (int it = 0; it < 5; ++it) {
                float Tr_d = 64.f / beta;
                float beta_new = Nc / (E_d + Tr_d);
                bool conv = fabsf(beta_new / beta0 - 1.f) < 0.02f;
                if (!done) { beta = beta_new; beta0 = beta_new; }
                done = done || conv;
            }
            ib_s = 1.f / beta;
        }
        out[OUT_W + b*64 + r] = wt;
        ws[WV_OFF + b*64 + r] = wt;
    }
    __syncthreads();

    // Mp emit (upper-tri, diag*0.5, * 1/beta) coalesced over 256 threads
    const float ib = ib_s;
    float* __restrict__ Mp = ws + MP_OFF + b * 4096;
    for (int e = t; e < 4096; e += 256) {
        const int row = e >> 6, j = e & 63;
        const float v = (j < row) ? 0.f
                      : ((j == row) ? 0.5f : 1.f) * W[row*65 + j] * ib;
        Mp[e] = v;
    }
}

// ============================================================
// Kernel 3: 2 pixels/thread: pred = w.b, var = 2*sum_i b_i*sum_{j>=i} Mp[i][j] b_j
// Mp staged in LDS (16KB), read via wave-uniform ds_read_b128 (broadcast,
// conflict-free) instead of 2080 scalar loads per pixel. bases as float2.
// Triangular loop quad-aligned: first quad of row i includes j<i zeros
// (stored as 0 in Mp), so results are exact.
// ============================================================
__global__ __launch_bounds__(256, 2) void predvar_kernel(
    const float* __restrict__ bases, const float* __restrict__ ws,
    float* __restrict__ out)
{
    __shared__ float Mp_s[4096];
    __shared__ float w_s[64];

    const int b = blockIdx.y;
    const int t = threadIdx.x;
    {
        const float4* __restrict__ src = (const float4*)(ws + MP_OFF + b * 4096);
        float4* dst = (float4*)Mp_s;
        for (int e = t; e < 1024; e += 256) dst[e] = src[e];
        if (t < 64) w_s[t] = ws[WV_OFF + b*64 + t];
    }
    __syncthreads();

    const int pix = (blockIdx.x * 256 + t) * 2;
    const float* basesb = bases + (long)b * NBASE * HW + pix;

    float2 bv[64];
    bv[0] = make_float2(1.f, 1.f);
#pragma unroll
    for (int c = 1; c < 64; c++)
        bv[c] = *(const float2*)&basesb[(long)(c - 1) * HW];

    float px = w_s[0], py = w_s[0];
#pragma unroll
    for (int c = 1; c < 64; c++) {
        px = fmaf(w_s[c], bv[c].x, px);
        py = fmaf(w_s[c], bv[c].y, py);
    }

    float vx = 0.f, vy = 0.f;
#pragma unroll
    for (int i = 0; i < 64; i++) {
        float sx = 0.f, sy2 = 0.f;
#pragma unroll
        for (int qd = i >> 2; qd < 16; qd++) {
            const float4 m = *(const float4*)&Mp_s[i*64 + 4*qd];
            sx  = fmaf(m.x, bv[4*qd+0].x, sx);
            sy2 = fmaf(m.x, bv[4*qd+0].y, sy2);
            sx  = fmaf(m.y, bv[4*qd+1].x, sx);
            sy2 = fmaf(m.y, bv[4*qd+1].y, sy2);
            sx  = fmaf(m.z, bv[4*qd+2].x, sx);
            sy2 = fmaf(m.z, bv[4*qd+2].y, sy2);
            sx  = fmaf(m.w, bv[4*qd+3].x, sx);
            sy2 = fmaf(m.w, bv[4*qd+3].y, sy2);
        }
        vx = fmaf(sx,  bv[i].x, vx);
        vy = fmaf(sy2, bv[i].y, vy);
    }

    *(float2*)&out[(long)b * HW + pix] = make_float2(px, py);
    *(float2*)&out[OUT_VAR + (long)b * HW + pix] = make_float2(2.f * vx, 2.f * vy);
}

extern "C" void kernel_launch(void* const* d_in, const int* in_sizes, int n_in,
                              void* d_out, int out_size, void* d_ws, size_t ws_size,
                              hipStream_t stream)
{
    const float* bases   = (const float*)d_in[0];
    const float* targets = (const float*)d_in[1];
    float* out = (float*)d_out;
    float* ws  = (float*)d_ws;

    // zero only the atomic-accumulated region (Xty/yty/N); XtX is written whole
    hipMemsetAsync(d_ws, 0, ZERO_FLOATS * sizeof(float), stream);

    // XtX partials staged in out[] (dead until reduce consumes them)
    gram_kernel<<<dim3(GRAM_BLKS, NB), 256, 0, stream>>>(bases, targets, ws, out);
    reduce_kernel<<<dim3(16, NB), 256, 0, stream>>>(out, ws);
    solve_kernel<<<NB, 256, 0, stream>>>(ws, out);
    predvar_kernel<<<dim3(HW / 512, NB), 256, 0, stream>>>(bases, ws, out);
}